// Round 3
// baseline (330.464 us; speedup 1.0000x reference)
//
#include <hip/hip_runtime.h>
#include <math.h>

#define HIDDEN 8

// native clang vectors — required for __builtin_nontemporal_* and guaranteed
// to lower to single dwordx4 loads/stores
typedef float  f32x4 __attribute__((ext_vector_type(4)));
typedef int    i32x4 __attribute__((ext_vector_type(4)));
typedef unsigned u32x4 __attribute__((ext_vector_type(4)));

__device__ __forceinline__ unsigned pack_bf16_pair(float lo, float hi) {
    union { float f; unsigned u; } a, b;
    a.f = lo; b.f = hi;
    unsigned lr = (a.u + 0x7fffu + ((a.u >> 16) & 1u)) >> 16;          // rne
    unsigned hr = (b.u + 0x7fffu + ((b.u >> 16) & 1u)) & 0xffff0000u;  // rne
    return lr | hr;
}

// ---- precompute per-node partial pre-activations ------------------------
//   u[i] = zd[i] @ W1[0:8]          (8 fp32 -> 4 packed bf16 dwords)
//   v[i] = zm[i] @ W1[8:16] + b1    (8 fp32 -> 4 packed bf16 dwords)
__global__ __launch_bounds__(256) void precompute_uv_kernel(
    const float* __restrict__ zd, const float* __restrict__ zm,
    const float* __restrict__ w1, const float* __restrict__ b1,
    unsigned* __restrict__ u, unsigned* __restrict__ v, int N)
{
    int i = blockIdx.x * blockDim.x + threadIdx.x;
    if (i < N) {
        float x[HIDDEN];
#pragma unroll
        for (int k = 0; k < HIDDEN; ++k) x[k] = zd[i * HIDDEN + k];
        float acc[HIDDEN];
#pragma unroll
        for (int j = 0; j < HIDDEN; ++j) acc[j] = 0.0f;
#pragma unroll
        for (int k = 0; k < HIDDEN; ++k) {
#pragma unroll
            for (int j = 0; j < HIDDEN; ++j)
                acc[j] = fmaf(x[k], w1[k * HIDDEN + j], acc[j]);
        }
#pragma unroll
        for (int p = 0; p < 4; ++p)
            u[i * 4 + p] = pack_bf16_pair(acc[2 * p], acc[2 * p + 1]);
    } else if (i < 2 * N) {
        int q = i - N;
        float x[HIDDEN];
#pragma unroll
        for (int k = 0; k < HIDDEN; ++k) x[k] = zm[q * HIDDEN + k];
        float acc[HIDDEN];
#pragma unroll
        for (int j = 0; j < HIDDEN; ++j) acc[j] = b1[j];
#pragma unroll
        for (int k = 0; k < HIDDEN; ++k) {
#pragma unroll
            for (int j = 0; j < HIDDEN; ++j)
                acc[j] = fmaf(x[k], w1[(HIDDEN + k) * HIDDEN + j], acc[j]);
        }
#pragma unroll
        for (int p = 0; p < 4; ++p)
            v[q * 4 + p] = pack_bf16_pair(acc[2 * p], acc[2 * p + 1]);
    }
}

// ---- edge kernel, 4 edges/thread ----------------------------------------
// dwordx4 index loads, 8 independent dwordx4 gathers issued back-to-back,
// dwordx4 nt store for the output stream.
__global__ __launch_bounds__(256) void edge_decoder_uv4_kernel(
    const u32x4* __restrict__ u,    // [N] packed bf16 (8 vals)
    const u32x4* __restrict__ v,    // [N]
    const i32x4* __restrict__ row4, const i32x4* __restrict__ col4,
    const float* __restrict__ w2, const float* __restrict__ b2,
    f32x4* __restrict__ out4, int E4, int N)
{
    int i = blockIdx.x * blockDim.x + threadIdx.x;
    if (i >= E4) return;

    i32x4 r = row4[i];
    i32x4 c = col4[i];

    int rr[4] = { r.x, r.y, r.z, r.w };
    int cc[4] = { c.x, c.y, c.z, c.w };
#pragma unroll
    for (int e = 0; e < 4; ++e) {
        rr[e] = min(max(rr[e], 0), N - 1);
        cc[e] = min(max(cc[e], 0), N - 1);
    }

    // issue all 8 scattered gathers before any use
    u32x4 pu[4], pv[4];
#pragma unroll
    for (int e = 0; e < 4; ++e) pu[e] = u[rr[e]];
#pragma unroll
    for (int e = 0; e < 4; ++e) pv[e] = v[cc[e]];

    float w2v[8];
#pragma unroll
    for (int j = 0; j < 8; ++j) w2v[j] = w2[j];
    float bias = b2[0];

    float o[4];
#pragma unroll
    for (int e = 0; e < 4; ++e) {
        unsigned q[4] = { pu[e].x, pu[e].y, pu[e].z, pu[e].w };
        unsigned s[4] = { pv[e].x, pv[e].y, pv[e].z, pv[e].w };
        float logit = bias;
#pragma unroll
        for (int k = 0; k < 4; ++k) {
            union { unsigned q; float f; } a0, a1, b0, b1u;
            a0.q = q[k] << 16;
            a1.q = q[k] & 0xffff0000u;
            b0.q = s[k] << 16;
            b1u.q = s[k] & 0xffff0000u;
            float h0 = a0.f + b0.f;
            float h1 = a1.f + b1u.f;
            if (h0 < 0.0f) h0 = 0.0f;
            if (h1 < 0.0f) h1 = 0.0f;
            logit = fmaf(h0, w2v[2 * k], logit);
            logit = fmaf(h1, w2v[2 * k + 1], logit);
        }
        o[e] = 1.0f / (1.0f + expf(-logit));
    }

    f32x4 ov;
    ov.x = o[0]; ov.y = o[1]; ov.z = o[2]; ov.w = o[3];
    __builtin_nontemporal_store(ov, out4 + i);
}

// ---- scalar edge kernel (tail / non-multiple-of-4 E) --------------------
__global__ __launch_bounds__(256) void edge_decoder_uv_kernel(
    const unsigned* __restrict__ u, const unsigned* __restrict__ v,
    const int* __restrict__ row, const int* __restrict__ col,
    const float* __restrict__ w2, const float* __restrict__ b2,
    float* __restrict__ out, int E, int N)
{
    int i = blockIdx.x * blockDim.x + threadIdx.x;
    if (i >= E) return;

    int r = row[i];
    int c = col[i];
    if (r < 0) r = 0;
    if (r > N - 1) r = N - 1;
    if (c < 0) c = 0;
    if (c > N - 1) c = N - 1;

    const unsigned* ur = u + (size_t)r * 4;
    const unsigned* vc = v + (size_t)c * 4;

    unsigned pu[4], pv[4];
#pragma unroll
    for (int k = 0; k < 4; ++k) pu[k] = ur[k];
#pragma unroll
    for (int k = 0; k < 4; ++k) pv[k] = vc[k];

    float logit = b2[0];
#pragma unroll
    for (int k = 0; k < 4; ++k) {
        union { unsigned q; float f; } a0, a1, b0, b1u;
        a0.q = pu[k] << 16;
        a1.q = pu[k] & 0xffff0000u;
        b0.q = pv[k] << 16;
        b1u.q = pv[k] & 0xffff0000u;
        float h0 = a0.f + b0.f;
        float h1 = a1.f + b1u.f;
        if (h0 < 0.0f) h0 = 0.0f;
        if (h1 < 0.0f) h1 = 0.0f;
        logit = fmaf(h0, w2[2 * k], logit);
        logit = fmaf(h1, w2[2 * k + 1], logit);
    }

    out[i] = 1.0f / (1.0f + expf(-logit));
}

// ---- fallback: fp32 full MLP (only if workspace too small) --------------
__global__ __launch_bounds__(256) void edge_decoder_f32_kernel(
    const float* __restrict__ zd, const float* __restrict__ zm,
    const int* __restrict__ row, const int* __restrict__ col,
    const float* __restrict__ w1, const float* __restrict__ b1,
    const float* __restrict__ w2, const float* __restrict__ b2,
    float* __restrict__ out, int E, int N)
{
    int i = blockIdx.x * blockDim.x + threadIdx.x;
    if (i >= E) return;
    int r = row[i];
    int c = col[i];
    if (r < 0) r = 0;
    if (r > N - 1) r = N - 1;
    if (c < 0) c = 0;
    if (c > N - 1) c = N - 1;
    const float* zdr = zd + (size_t)r * HIDDEN;
    const float* zmc = zm + (size_t)c * HIDDEN;
    float z[16];
#pragma unroll
    for (int k = 0; k < HIDDEN; ++k) z[k] = zdr[k];
#pragma unroll
    for (int k = 0; k < HIDDEN; ++k) z[HIDDEN + k] = zmc[k];
    float h[HIDDEN];
#pragma unroll
    for (int j = 0; j < HIDDEN; ++j) h[j] = b1[j];
#pragma unroll
    for (int k = 0; k < 2 * HIDDEN; ++k) {
        float zk = z[k];
#pragma unroll
        for (int j = 0; j < HIDDEN; ++j)
            h[j] = fmaf(zk, w1[k * HIDDEN + j], h[j]);
    }
    float logit = b2[0];
#pragma unroll
    for (int j = 0; j < HIDDEN; ++j) {
        float hj = h[j] > 0.0f ? h[j] : 0.0f;
        logit = fmaf(hj, w2[j], logit);
    }
    out[i] = 1.0f / (1.0f + expf(-logit));
}

extern "C" void kernel_launch(void* const* d_in, const int* in_sizes, int n_in,
                              void* d_out, int out_size, void* d_ws, size_t ws_size,
                              hipStream_t stream) {
    const float* zd  = (const float*)d_in[0];
    const float* zm  = (const float*)d_in[1];
    const int*   eli = (const int*)d_in[2];   // [2, E] flat: row then col
    const float* w1  = (const float*)d_in[3];
    const float* b1  = (const float*)d_in[4];
    const float* w2  = (const float*)d_in[5];
    const float* b2  = (const float*)d_in[6];
    float* out = (float*)d_out;

    int E = out_size;                 // 16,000,000
    int N = in_sizes[0] / HIDDEN;     // 100,000
    if (E <= 0 || N <= 0) return;

    const int* row = eli;
    const int* col = eli + E;
    const int block = 256;

    size_t tbl_bytes = (size_t)N * 4 * sizeof(unsigned);   // 1.6 MB per table
    if (ws_size >= 2 * tbl_bytes) {
        unsigned* u = (unsigned*)d_ws;
        unsigned* v = u + (size_t)N * 4;

        int pgrid = (2 * N + block - 1) / block;
        precompute_uv_kernel<<<pgrid, block, 0, stream>>>(zd, zm, w1, b1, u, v, N);

        if ((E & 3) == 0) {
            // vector path: 4 edges/thread (E multiple of 4 keeps col4 16B-aligned)
            int E4 = E >> 2;
            int grid = (E4 + block - 1) / block;
            edge_decoder_uv4_kernel<<<grid, block, 0, stream>>>(
                (const u32x4*)u, (const u32x4*)v,
                (const i32x4*)row, (const i32x4*)col,
                w2, b2, (f32x4*)out, E4, N);
        } else {
            int grid = (E + block - 1) / block;
            edge_decoder_uv_kernel<<<grid, block, 0, stream>>>(
                u, v, row, col, w2, b2, out, E, N);
        }
    } else {
        int grid = (E + block - 1) / block;
        edge_decoder_f32_kernel<<<grid, block, 0, stream>>>(
            zd, zm, row, col, w1, b1, w2, b2, out, E, N);
    }
}